// Round 4
// baseline (904.483 us; speedup 1.0000x reference)
//
#include <hip/hip_runtime.h>
#include <hip/hip_bf16.h>
#include <hip/hip_fp16.h>

// GCN 2-layer inference, N=100000, E=1600000, F_IN=100, H=128, C=47.
// R4: (a) XCD-sliced aggregation: features split into 8 slices x 16, slice
// working set 3.2MB fits one XCD's 4MB L2; blockIdx%8 pins a slice to an XCD.
// (b) layer-2 GEMM commuted past aggregation: agg2 sums h' = dinv*relu(...)
// (128 feats, same sliced kernel as agg1), gemm2 runs on dense aggregated
// rows. (c) scatter fused with gemm1 (independent work, 1:4 interleave).
// Edge streams use nontemporal loads to keep L2 for the gather slice.

constexpr int N    = 100000;
constexpr int E    = 1600000;
constexpr int FIN  = 100;
constexpr int HD   = 128;
constexpr int C    = 47;
constexpr int EN   = E + N;          // edges + self loops
constexpr int SCAN_CHUNK = 2048;     // 256 threads * 8
constexpr int NB_SCAN = (N + SCAN_CHUNK - 1) / SCAN_CHUNK;  // 49
constexpr int G_GEMM1 = (N + 63) / 64;        // 1563
constexpr int G_SCAT  = (E + 255) / 256;      // 6250
constexpr int G_CHUNK = (N + 63) / 64;        // 1563 (64 nodes per block, 16/wave)

// ---------- CSR build ----------

__global__ void init_cnt(int* __restrict__ cnt) {
    int i = blockIdx.x * 256 + threadIdx.x;
    if (i < N) cnt[i] = 1;   // self loop occupies slot 0 of every node
}

// count degrees AND record each edge's slot within its dst node (>=1)
__global__ void count_pos(const int* __restrict__ dst, int* __restrict__ cnt,
                          int* __restrict__ epos) {
    int e = blockIdx.x * 256 + threadIdx.x;
    if (e < E) {
        int d = __builtin_nontemporal_load(&dst[e]);
        int p = atomicAdd(&cnt[d], 1);
        __builtin_nontemporal_store(p, &epos[e]);
    }
}

__global__ void scan_pass1(const int* __restrict__ cnt, int* __restrict__ partials) {
    int t = threadIdx.x, b = blockIdx.x;
    int base = b * SCAN_CHUNK + t * 8;
    int s = 0;
#pragma unroll
    for (int i = 0; i < 8; ++i) {
        int idx = base + i;
        if (idx < N) s += cnt[idx];
    }
    __shared__ int sm[256];
    sm[t] = s;
    __syncthreads();
    for (int off = 128; off > 0; off >>= 1) {
        if (t < off) sm[t] += sm[t + off];
        __syncthreads();
    }
    if (t == 0) partials[b] = sm[0];
}

__global__ void scan_pass2(const int* __restrict__ partials, int* __restrict__ pscan,
                           int* __restrict__ rowptr) {
    if (threadIdx.x == 0) {
        int run = 0;
        for (int i = 0; i < NB_SCAN; ++i) { pscan[i] = run; run += partials[i]; }
        rowptr[N] = run;   // == E + N
    }
}

// rowptr + dinv + self-loop slot in one pass
__global__ void scan_pass3(const int* __restrict__ cnt, const int* __restrict__ pscan,
                           int* __restrict__ rowptr, float* __restrict__ dinv,
                           int* __restrict__ ep) {
    int t = threadIdx.x, b = blockIdx.x;
    int base = b * SCAN_CHUNK + t * 8;
    int v[8];
    int s = 0;
#pragma unroll
    for (int i = 0; i < 8; ++i) {
        int idx = base + i;
        v[i] = (idx < N) ? cnt[idx] : 0;
        s += v[i];
    }
    __shared__ int sm[256];
    sm[t] = s;
    __syncthreads();
    for (int off = 1; off < 256; off <<= 1) {
        int tv = (t >= off) ? sm[t - off] : 0;
        __syncthreads();
        sm[t] += tv;
        __syncthreads();
    }
    int excl = sm[t] - s + pscan[b];
#pragma unroll
    for (int i = 0; i < 8; ++i) {
        int idx = base + i;
        if (idx < N) {
            rowptr[idx] = excl;
            ep[excl] = idx;                  // self loop at slot 0
            dinv[idx] = rsqrtf((float)v[i]); // deg >= 1 always
            excl += v[i];
        }
    }
}

// ---------- fused: scatter_edges + gemm1 ----------
// xw (fp16, SLICED layout [slice][node][16]) = dinv[n] * (x[N,100] @ W1)
// block role: b%5==0 -> gemm block b/5 (1563); else scatter block b/5*4+b%5-1 (6250)

__global__ __launch_bounds__(256) void scatter_gemm1(
        const float* __restrict__ x, const float* __restrict__ W1,
        const float* __restrict__ dinv,
        const int* __restrict__ ei, const int* __restrict__ rowptr,
        const int* __restrict__ epos, int* __restrict__ ep,
        __half* __restrict__ xwh) {
    int b = blockIdx.x, r = b % 5, g = b / 5;
    if (r != 0) {
        // ----- scatter role -----
        int sb = g * 4 + (r - 1);
        if (sb < G_SCAT) {
            int e = sb * 256 + threadIdx.x;
            if (e < E) {
                int s = __builtin_nontemporal_load(&ei[e]);
                int d = __builtin_nontemporal_load(&ei[E + e]);
                int p = __builtin_nontemporal_load(&epos[e]);
                ep[rowptr[d] + p] = s;
            }
        }
        return;
    }
    // ----- gemm1 role -----
    __shared__ float sW[FIN * HD];     // 12800 floats
    __shared__ float sX[64 * FIN];     // 6400 floats
    int tx = threadIdx.x;
    size_t node0 = (size_t)g * 64;

    const float4* W4 = (const float4*)W1;
    for (int i = tx; i < FIN * HD / 4; i += 256) ((float4*)sW)[i] = W4[i];
    size_t base4 = node0 * FIN / 4;          // node0*100 divisible by 4
    const float4* x4 = (const float4*)x;
    for (int i = tx; i < 64 * FIN / 4; i += 256) {
        size_t gg = base4 + i;
        ((float4*)sX)[i] = (gg < (size_t)N * FIN / 4) ? x4[gg]
                                                      : make_float4(0.f, 0.f, 0.f, 0.f);
    }
    __syncthreads();

    int col = (tx & 31) * 4;        // 0..124, multiple of 4
    int nb  = (tx >> 5) * 8;        // 0..56
    float4 acc[8];
#pragma unroll
    for (int i = 0; i < 8; ++i) acc[i] = make_float4(0.f, 0.f, 0.f, 0.f);

    for (int k = 0; k < FIN; ++k) {
        float4 bb = *(const float4*)&sW[k * HD + col];
#pragma unroll
        for (int i = 0; i < 8; ++i) {
            float a = sX[(nb + i) * FIN + k];
            acc[i].x = fmaf(a, bb.x, acc[i].x);
            acc[i].y = fmaf(a, bb.y, acc[i].y);
            acc[i].z = fmaf(a, bb.z, acc[i].z);
            acc[i].w = fmaf(a, bb.w, acc[i].w);
        }
    }
    int slice = col >> 4;           // 0..7
    int within = col & 15;          // 0,4,8,12
#pragma unroll
    for (int i = 0; i < 8; ++i) {
        size_t node = node0 + nb + i;
        if (node < (size_t)N) {
            float dv = dinv[node];
            union { __half2 h2[2]; uint2 u; } p;
            p.h2[0] = __floats2half2_rn(acc[i].x * dv, acc[i].y * dv);
            p.h2[1] = __floats2half2_rn(acc[i].z * dv, acc[i].w * dv);
            *(uint2*)&xwh[(size_t)slice * (N * 16) + node * 16 + within] = p.u;
        }
    }
}

// ---------- sliced aggregation ----------
// slice = blockIdx%8 (pins to XCD via round-robin); 4 waves/block, 16 nodes/wave.
// wave lanes: sub = lane>>3 (edge subgroup), fl = lane&7 (half2 feature index).
// L1=true:  dst = dinv*relu(bias + dinv*sum)   (h' for layer 2)
// L1=false: dst = sum                           (g = sum of h')

template<bool L1>
__global__ __launch_bounds__(256) void agg_sliced(
        const __half2* __restrict__ src, const int* __restrict__ rowptr,
        const int* __restrict__ ep, const float* __restrict__ dinv,
        const float* __restrict__ bias, __half2* __restrict__ dst) {
    int slice = blockIdx.x & 7;
    int chunk = blockIdx.x >> 3;
    int lane = threadIdx.x & 63;
    int sub = lane >> 3, fl = lane & 7;
    int nbase = chunk * 64 + (threadIdx.x >> 6) * 16;
    if (nbase >= N) return;
    const __half2* xs = src + (size_t)slice * (N * 8);

    int rpidx = nbase + lane;
    int rp = rowptr[rpidx <= N ? rpidx : N];   // lanes 0..16 useful

    for (int t = 0; t < 16; ++t) {
        int node = nbase + t;
        if (node >= N) break;
        int beg = __shfl(rp, t), end = __shfl(rp, t + 1);
        float ax = 0.f, ay = 0.f;
        for (int base = beg; base < end; base += 8) {
            int idx = base + sub;
            bool ok = idx < end;
            int s = __builtin_nontemporal_load(ep + (ok ? idx : beg));
            float2 f = __half22float2(xs[(size_t)s * 8 + fl]);
            if (ok) { ax += f.x; ay += f.y; }
        }
#pragma unroll
        for (int d = 8; d < 64; d <<= 1) {
            ax += __shfl_xor(ax, d);
            ay += __shfl_xor(ay, d);
        }
        if (sub == 0) {
            float ox, oy;
            if (L1) {
                float dv = dinv[node];
                float bx = bias[slice * 16 + fl * 2];
                float by = bias[slice * 16 + fl * 2 + 1];
                ox = dv * fmaxf(fmaf(dv, ax, bx), 0.f);
                oy = dv * fmaxf(fmaf(dv, ay, by), 0.f);
            } else {
                ox = ax; oy = ay;
            }
            dst[(size_t)slice * (N * 8) + (size_t)node * 8 + fl] = __floats2half2_rn(ox, oy);
        }
    }
}

// ---------- gemm2: out[N,47] (fp32) = b2 + dinv[n] * (g[n] @ W2[128,47]) ----------
// g read from sliced fp16 layout.

__global__ __launch_bounds__(256) void gemm2s(const __half2* __restrict__ gh2,
                                              const float* __restrict__ W2,
                                              const float* __restrict__ dinv,
                                              const float* __restrict__ b2,
                                              float* __restrict__ out) {
    __shared__ float sH[64 * 130];     // padded stride 130
    __shared__ float sW[HD * 48];      // padded to 48 cols
    int tx = threadIdx.x;
    size_t node0 = (size_t)blockIdx.x * 64;

    for (int i = tx; i < HD * 48; i += 256) {
        int k = i / 48, c = i - k * 48;
        sW[i] = (c < C) ? W2[k * C + c] : 0.f;
    }
    for (int i = tx; i < 64 * 64; i += 256) {
        int nl = i >> 6, f2 = i & 63;
        int feat = f2 * 2;
        int slice = feat >> 4;
        int within = (feat & 15) >> 1;     // half2 index within slice
        size_t node = node0 + nl;
        float2 f = make_float2(0.f, 0.f);
        if (node < (size_t)N)
            f = __half22float2(gh2[(size_t)slice * (N * 8) + node * 8 + within]);
        sH[nl * 130 + feat]     = f.x;
        sH[nl * 130 + feat + 1] = f.y;
    }
    __syncthreads();

    int c0 = (tx & 15) * 3;        // 0..45
    int nb = (tx >> 4) * 4;        // 0..60
    float acc[4][3] = {};
    for (int k = 0; k < HD; ++k) {
        float w0 = sW[k * 48 + c0];
        float w1 = sW[k * 48 + c0 + 1];
        float w2 = sW[k * 48 + c0 + 2];
#pragma unroll
        for (int i = 0; i < 4; ++i) {
            float a = sH[(nb + i) * 130 + k];
            acc[i][0] = fmaf(a, w0, acc[i][0]);
            acc[i][1] = fmaf(a, w1, acc[i][1]);
            acc[i][2] = fmaf(a, w2, acc[i][2]);
        }
    }
#pragma unroll
    for (int i = 0; i < 4; ++i) {
        size_t node = node0 + nb + i;
        if (node < (size_t)N) {
            float dv = dinv[node];
#pragma unroll
            for (int jj = 0; jj < 3; ++jj) {
                int c = c0 + jj;
                if (c < C) out[node * C + c] = fmaf(acc[i][jj], dv, b2[c]);
            }
        }
    }
}

extern "C" void kernel_launch(void* const* d_in, const int* in_sizes, int n_in,
                              void* d_out, int out_size, void* d_ws, size_t ws_size,
                              hipStream_t stream) {
    const float* x  = (const float*)d_in[0];
    const int*   ei = (const int*)d_in[1];
    const float* W1 = (const float*)d_in[2];
    const float* b1 = (const float*)d_in[3];
    const float* W2 = (const float*)d_in[4];
    const float* b2 = (const float*)d_in[5];
    float* out = (float*)d_out;

    size_t off = 0;
    auto alloc = [&](size_t bytes) {
        void* p = (char*)d_ws + off;
        off += (bytes + 255) & ~(size_t)255;
        return p;
    };
    int*     cnt      = (int*)alloc((size_t)N * 4);
    int*     rowptr   = (int*)alloc((size_t)(N + 1) * 4);
    int*     epos     = (int*)alloc((size_t)E * 4);
    int*     partials = (int*)alloc(64 * 4);
    int*     pscan    = (int*)alloc(64 * 4);
    float*   dinv     = (float*)alloc((size_t)N * 4);
    int*     ep       = (int*)alloc((size_t)EN * 4);
    __half*  xwh      = (__half*)alloc((size_t)N * HD * 2);   // sliced [8][N][16]
    __half*  hph      = (__half*)alloc((size_t)N * HD * 2);   // sliced h'
    __half*  gh       = (__half*)alloc((size_t)N * HD * 2);   // sliced g
    (void)ws_size;

    int gN = (N + 255) / 256;
    int gE = (E + 255) / 256;

    init_cnt<<<gN, 256, 0, stream>>>(cnt);
    count_pos<<<gE, 256, 0, stream>>>(ei + E, cnt, epos);
    scan_pass1<<<NB_SCAN, 256, 0, stream>>>(cnt, partials);
    scan_pass2<<<1, 64, 0, stream>>>(partials, pscan, rowptr);
    scan_pass3<<<NB_SCAN, 256, 0, stream>>>(cnt, pscan, rowptr, dinv, ep);

    scatter_gemm1<<<G_GEMM1 * 5, 256, 0, stream>>>(x, W1, dinv, ei, rowptr, epos, ep, xwh);

    agg_sliced<true><<<G_CHUNK * 8, 256, 0, stream>>>(
        (const __half2*)xwh, rowptr, ep, dinv, b1, (__half2*)hph);
    agg_sliced<false><<<G_CHUNK * 8, 256, 0, stream>>>(
        (const __half2*)hph, rowptr, ep, dinv, b1, (__half2*)gh);

    gemm2s<<<(N + 63) / 64, 256, 0, stream>>>((const __half2*)gh, W2, dinv, b2, out);
}

// Round 5
// 641.993 us; speedup vs baseline: 1.4089x; 1.4089x over previous
//
#include <hip/hip_runtime.h>
#include <hip/hip_bf16.h>
#include <hip/hip_fp16.h>

// GCN 2-layer inference, N=100000, E=1600000, F_IN=100, H=128, C=47.
// R5: keep R4's XCD-sliced layout (slice working set 3.2MB fits one XCD L2;
// FETCH dropped 190->72MB) but fix the agg structure that caused the 2x
// regression: lane-group-of-8 = one node, 8 half2 features per lane group,
// private per-group edge loop with 8-way unroll -> 64 independent gathers in
// flight per wave, NO shuffle reductions, contiguous 256B wave stores.
// gemm2 stays commuted past aggregation; scatter stays fused with gemm1.

constexpr int N    = 100000;
constexpr int E    = 1600000;
constexpr int FIN  = 100;
constexpr int HD   = 128;
constexpr int C    = 47;
constexpr int EN   = E + N;          // edges + self loops
constexpr int SCAN_CHUNK = 2048;     // 256 threads * 8
constexpr int NB_SCAN = (N + SCAN_CHUNK - 1) / SCAN_CHUNK;  // 49
constexpr int G_GEMM1 = (N + 63) / 64;        // 1563
constexpr int G_SCAT  = (E + 255) / 256;      // 6250

// ---------- CSR build ----------

__global__ void init_cnt(int* __restrict__ cnt) {
    int i = blockIdx.x * 256 + threadIdx.x;
    if (i < N) cnt[i] = 1;   // self loop occupies slot 0 of every node
}

// count degrees AND record each edge's slot within its dst node (>=1)
__global__ void count_pos(const int* __restrict__ dst, int* __restrict__ cnt,
                          int* __restrict__ epos) {
    int e = blockIdx.x * 256 + threadIdx.x;
    if (e < E) {
        int d = __builtin_nontemporal_load(&dst[e]);
        int p = atomicAdd(&cnt[d], 1);
        __builtin_nontemporal_store(p, &epos[e]);
    }
}

__global__ void scan_pass1(const int* __restrict__ cnt, int* __restrict__ partials) {
    int t = threadIdx.x, b = blockIdx.x;
    int base = b * SCAN_CHUNK + t * 8;
    int s = 0;
#pragma unroll
    for (int i = 0; i < 8; ++i) {
        int idx = base + i;
        if (idx < N) s += cnt[idx];
    }
    __shared__ int sm[256];
    sm[t] = s;
    __syncthreads();
    for (int off = 128; off > 0; off >>= 1) {
        if (t < off) sm[t] += sm[t + off];
        __syncthreads();
    }
    if (t == 0) partials[b] = sm[0];
}

__global__ void scan_pass2(const int* __restrict__ partials, int* __restrict__ pscan,
                           int* __restrict__ rowptr) {
    if (threadIdx.x == 0) {
        int run = 0;
        for (int i = 0; i < NB_SCAN; ++i) { pscan[i] = run; run += partials[i]; }
        rowptr[N] = run;   // == E + N
    }
}

// rowptr + dinv + self-loop slot in one pass
__global__ void scan_pass3(const int* __restrict__ cnt, const int* __restrict__ pscan,
                           int* __restrict__ rowptr, float* __restrict__ dinv,
                           int* __restrict__ ep) {
    int t = threadIdx.x, b = blockIdx.x;
    int base = b * SCAN_CHUNK + t * 8;
    int v[8];
    int s = 0;
#pragma unroll
    for (int i = 0; i < 8; ++i) {
        int idx = base + i;
        v[i] = (idx < N) ? cnt[idx] : 0;
        s += v[i];
    }
    __shared__ int sm[256];
    sm[t] = s;
    __syncthreads();
    for (int off = 1; off < 256; off <<= 1) {
        int tv = (t >= off) ? sm[t - off] : 0;
        __syncthreads();
        sm[t] += tv;
        __syncthreads();
    }
    int excl = sm[t] - s + pscan[b];
#pragma unroll
    for (int i = 0; i < 8; ++i) {
        int idx = base + i;
        if (idx < N) {
            rowptr[idx] = excl;
            ep[excl] = idx;                  // self loop at slot 0
            dinv[idx] = rsqrtf((float)v[i]); // deg >= 1 always
            excl += v[i];
        }
    }
}

// ---------- fused: scatter_edges + gemm1 ----------
// xw (fp16, SLICED layout [slice][node][16]) = dinv[n] * (x[N,100] @ W1)

__global__ __launch_bounds__(256) void scatter_gemm1(
        const float* __restrict__ x, const float* __restrict__ W1,
        const float* __restrict__ dinv,
        const int* __restrict__ ei, const int* __restrict__ rowptr,
        const int* __restrict__ epos, int* __restrict__ ep,
        __half* __restrict__ xwh) {
    int b = blockIdx.x, r = b % 5, g = b / 5;
    if (r != 0) {
        // ----- scatter role -----
        int sb = g * 4 + (r - 1);
        if (sb < G_SCAT) {
            int e = sb * 256 + threadIdx.x;
            if (e < E) {
                int s = __builtin_nontemporal_load(&ei[e]);
                int d = __builtin_nontemporal_load(&ei[E + e]);
                int p = __builtin_nontemporal_load(&epos[e]);
                ep[rowptr[d] + p] = s;
            }
        }
        return;
    }
    // ----- gemm1 role -----
    __shared__ float sW[FIN * HD];     // 12800 floats
    __shared__ float sX[64 * FIN];     // 6400 floats
    int tx = threadIdx.x;
    size_t node0 = (size_t)g * 64;

    const float4* W4 = (const float4*)W1;
    for (int i = tx; i < FIN * HD / 4; i += 256) ((float4*)sW)[i] = W4[i];
    size_t base4 = node0 * FIN / 4;          // node0*100 divisible by 4
    const float4* x4 = (const float4*)x;
    for (int i = tx; i < 64 * FIN / 4; i += 256) {
        size_t gg = base4 + i;
        ((float4*)sX)[i] = (gg < (size_t)N * FIN / 4) ? x4[gg]
                                                      : make_float4(0.f, 0.f, 0.f, 0.f);
    }
    __syncthreads();

    int col = (tx & 31) * 4;        // 0..124, multiple of 4
    int nb  = (tx >> 5) * 8;        // 0..56
    float4 acc[8];
#pragma unroll
    for (int i = 0; i < 8; ++i) acc[i] = make_float4(0.f, 0.f, 0.f, 0.f);

    for (int k = 0; k < FIN; ++k) {
        float4 bb = *(const float4*)&sW[k * HD + col];
#pragma unroll
        for (int i = 0; i < 8; ++i) {
            float a = sX[(nb + i) * FIN + k];
            acc[i].x = fmaf(a, bb.x, acc[i].x);
            acc[i].y = fmaf(a, bb.y, acc[i].y);
            acc[i].z = fmaf(a, bb.z, acc[i].z);
            acc[i].w = fmaf(a, bb.w, acc[i].w);
        }
    }
    int slice = col >> 4;           // 0..7
    int within = col & 15;          // 0,4,8,12
#pragma unroll
    for (int i = 0; i < 8; ++i) {
        size_t node = node0 + nb + i;
        if (node < (size_t)N) {
            float dv = dinv[node];
            union { __half2 h2[2]; uint2 u; } p;
            p.h2[0] = __floats2half2_rn(acc[i].x * dv, acc[i].y * dv);
            p.h2[1] = __floats2half2_rn(acc[i].z * dv, acc[i].w * dv);
            *(uint2*)&xwh[(size_t)slice * (N * 16) + node * 16 + within] = p.u;
        }
    }
}

// ---------- sliced aggregation, group-per-node ----------
// slice = blockIdx&7 (XCD round-robin pin). Block = 256 threads = 32 nodes.
// Lane group of 8 = one node: fl = lane&7 indexes the slice's 8 half2 feats.
// Each group privately walks its edge list, 8-way unrolled -> 8 independent
// gathers in flight per group (64/wave), no cross-lane ops, accumulator IS
// the output feature. Store: 8 consecutive nodes x 32B = 256B per wave.
// L1=true:  dst = dinv*relu(bias + dinv*sum)   (h' for layer 2)
// L1=false: dst = sum                           (g = sum of h')

template<bool L1>
__global__ __launch_bounds__(256) void agg_sliced(
        const __half2* __restrict__ src, const int* __restrict__ rowptr,
        const int* __restrict__ ep, const float* __restrict__ dinv,
        const float* __restrict__ bias, __half2* __restrict__ dst) {
    int slice = blockIdx.x & 7;
    int chunk = blockIdx.x >> 3;
    int lane = threadIdx.x & 63;
    int grp = lane >> 3, fl = lane & 7;
    int node = chunk * 32 + (threadIdx.x >> 6) * 8 + grp;
    if (node >= N) return;
    const __half2* xs = src + (size_t)slice * (N * 8);

    int beg = rowptr[node], end = rowptr[node + 1];
    float ax = 0.f, ay = 0.f;
    int j = beg;
    for (; j + 8 <= end; j += 8) {
        int s0 = __builtin_nontemporal_load(ep + j + 0);
        int s1 = __builtin_nontemporal_load(ep + j + 1);
        int s2 = __builtin_nontemporal_load(ep + j + 2);
        int s3 = __builtin_nontemporal_load(ep + j + 3);
        int s4 = __builtin_nontemporal_load(ep + j + 4);
        int s5 = __builtin_nontemporal_load(ep + j + 5);
        int s6 = __builtin_nontemporal_load(ep + j + 6);
        int s7 = __builtin_nontemporal_load(ep + j + 7);
        __half2 v0 = xs[(size_t)s0 * 8 + fl];
        __half2 v1 = xs[(size_t)s1 * 8 + fl];
        __half2 v2 = xs[(size_t)s2 * 8 + fl];
        __half2 v3 = xs[(size_t)s3 * 8 + fl];
        __half2 v4 = xs[(size_t)s4 * 8 + fl];
        __half2 v5 = xs[(size_t)s5 * 8 + fl];
        __half2 v6 = xs[(size_t)s6 * 8 + fl];
        __half2 v7 = xs[(size_t)s7 * 8 + fl];
        float2 f;
        f = __half22float2(v0); ax += f.x; ay += f.y;
        f = __half22float2(v1); ax += f.x; ay += f.y;
        f = __half22float2(v2); ax += f.x; ay += f.y;
        f = __half22float2(v3); ax += f.x; ay += f.y;
        f = __half22float2(v4); ax += f.x; ay += f.y;
        f = __half22float2(v5); ax += f.x; ay += f.y;
        f = __half22float2(v6); ax += f.x; ay += f.y;
        f = __half22float2(v7); ax += f.x; ay += f.y;
    }
    for (; j < end; ++j) {
        int s = __builtin_nontemporal_load(ep + j);
        float2 f = __half22float2(xs[(size_t)s * 8 + fl]);
        ax += f.x; ay += f.y;
    }

    float ox, oy;
    if (L1) {
        float dv = dinv[node];
        float bx = bias[slice * 16 + fl * 2];
        float by = bias[slice * 16 + fl * 2 + 1];
        ox = dv * fmaxf(fmaf(dv, ax, bx), 0.f);
        oy = dv * fmaxf(fmaf(dv, ay, by), 0.f);
    } else {
        ox = ax; oy = ay;
    }
    dst[(size_t)slice * (N * 8) + (size_t)node * 8 + fl] = __floats2half2_rn(ox, oy);
}

// ---------- gemm2: out[N,47] (fp32) = b2 + dinv[n] * (g[n] @ W2[128,47]) ----------
// g read from sliced fp16 layout.

__global__ __launch_bounds__(256) void gemm2s(const __half2* __restrict__ gh2,
                                              const float* __restrict__ W2,
                                              const float* __restrict__ dinv,
                                              const float* __restrict__ b2,
                                              float* __restrict__ out) {
    __shared__ float sH[64 * 130];     // padded stride 130
    __shared__ float sW[HD * 48];      // padded to 48 cols
    int tx = threadIdx.x;
    size_t node0 = (size_t)blockIdx.x * 64;

    for (int i = tx; i < HD * 48; i += 256) {
        int k = i / 48, c = i - k * 48;
        sW[i] = (c < C) ? W2[k * C + c] : 0.f;
    }
    for (int i = tx; i < 64 * 64; i += 256) {
        int nl = i >> 6, f2 = i & 63;
        int feat = f2 * 2;
        int slice = feat >> 4;
        int within = (feat & 15) >> 1;     // half2 index within slice
        size_t node = node0 + nl;
        float2 f = make_float2(0.f, 0.f);
        if (node < (size_t)N)
            f = __half22float2(gh2[(size_t)slice * (N * 8) + node * 8 + within]);
        sH[nl * 130 + feat]     = f.x;
        sH[nl * 130 + feat + 1] = f.y;
    }
    __syncthreads();

    int c0 = (tx & 15) * 3;        // 0..45
    int nb = (tx >> 4) * 4;        // 0..60
    float acc[4][3] = {};
    for (int k = 0; k < HD; ++k) {
        float w0 = sW[k * 48 + c0];
        float w1 = sW[k * 48 + c0 + 1];
        float w2 = sW[k * 48 + c0 + 2];
#pragma unroll
        for (int i = 0; i < 4; ++i) {
            float a = sH[(nb + i) * 130 + k];
            acc[i][0] = fmaf(a, w0, acc[i][0]);
            acc[i][1] = fmaf(a, w1, acc[i][1]);
            acc[i][2] = fmaf(a, w2, acc[i][2]);
        }
    }
#pragma unroll
    for (int i = 0; i < 4; ++i) {
        size_t node = node0 + nb + i;
        if (node < (size_t)N) {
            float dv = dinv[node];
#pragma unroll
            for (int jj = 0; jj < 3; ++jj) {
                int c = c0 + jj;
                if (c < C) out[node * C + c] = fmaf(acc[i][jj], dv, b2[c]);
            }
        }
    }
}

extern "C" void kernel_launch(void* const* d_in, const int* in_sizes, int n_in,
                              void* d_out, int out_size, void* d_ws, size_t ws_size,
                              hipStream_t stream) {
    const float* x  = (const float*)d_in[0];
    const int*   ei = (const int*)d_in[1];
    const float* W1 = (const float*)d_in[2];
    const float* b1 = (const float*)d_in[3];
    const float* W2 = (const float*)d_in[4];
    const float* b2 = (const float*)d_in[5];
    float* out = (float*)d_out;

    size_t off = 0;
    auto alloc = [&](size_t bytes) {
        void* p = (char*)d_ws + off;
        off += (bytes + 255) & ~(size_t)255;
        return p;
    };
    int*     cnt      = (int*)alloc((size_t)N * 4);
    int*     rowptr   = (int*)alloc((size_t)(N + 1) * 4);
    int*     epos     = (int*)alloc((size_t)E * 4);
    int*     partials = (int*)alloc(64 * 4);
    int*     pscan    = (int*)alloc(64 * 4);
    float*   dinv     = (float*)alloc((size_t)N * 4);
    int*     ep       = (int*)alloc((size_t)EN * 4);
    __half*  xwh      = (__half*)alloc((size_t)N * HD * 2);   // sliced [8][N][16]
    __half*  hph      = (__half*)alloc((size_t)N * HD * 2);   // sliced h'
    __half*  gh       = (__half*)alloc((size_t)N * HD * 2);   // sliced g
    (void)ws_size;

    int gN = (N + 255) / 256;
    int gE = (E + 255) / 256;

    init_cnt<<<gN, 256, 0, stream>>>(cnt);
    count_pos<<<gE, 256, 0, stream>>>(ei + E, cnt, epos);
    scan_pass1<<<NB_SCAN, 256, 0, stream>>>(cnt, partials);
    scan_pass2<<<1, 64, 0, stream>>>(partials, pscan, rowptr);
    scan_pass3<<<NB_SCAN, 256, 0, stream>>>(cnt, pscan, rowptr, dinv, ep);

    scatter_gemm1<<<G_GEMM1 * 5, 256, 0, stream>>>(x, W1, dinv, ei, rowptr, epos, ep, xwh);

    int gAgg = ((N + 31) / 32) * 8;   // 25000 blocks: slice = blockIdx&7
    agg_sliced<true><<<gAgg, 256, 0, stream>>>(
        (const __half2*)xwh, rowptr, ep, dinv, b1, (__half2*)hph);
    agg_sliced<false><<<gAgg, 256, 0, stream>>>(
        (const __half2*)hph, rowptr, ep, dinv, b1, (__half2*)gh);

    gemm2s<<<(N + 63) / 64, 256, 0, stream>>>((const __half2*)gh, W2, dinv, b2, out);
}